// Round 4
// baseline (1637.275 us; speedup 1.0000x reference)
//
#include <hip/hip_runtime.h>
#include <math.h>

// Problem constants
#define NB 64
#define NN 4096
#define ND 128
#define NS 8
#define NH 256
#define CHUNKS 16            // attn blocks per batch
#define ROWS_PER_CHUNK 256   // NN / CHUNKS

static constexpr float EPSA  = 1e-8f;
static constexpr float LNE   = 1e-5f;
static constexpr float SCALE = 0.08838834764831845f;  // 1/sqrt(128)

// ---- workspace layout (float offsets) ----
#define OFF_SLOTS 0                        // [64][8][128]
#define OFF_QK    65536                    // [64][8][128]
#define OFF_WC    131072                   // [384][128]  W_ih @ Wv
#define OFF_M2T   180224                   // [128][128]
#define OFF_QKB   196608                   // [128]
#define OFF_UPD   196736                   // [64][8][128] reduced raw updates
#define OFF_CS    262272                   // [64][8]      reduced colsums
#define OFF_PART  262784                   // [64][16][8][128] partial updates
#define OFF_PCS   1311360                  // [64][16][8]      partial colsums

__device__ __forceinline__ float dot4f(float4 a, float4 b) {
    return fmaf(a.x, b.x, fmaf(a.y, b.y, fmaf(a.z, b.z, a.w * b.w)));
}

// DPP-based lane-group reductions (VALU pipe, no LDS).
// quad_perm[1,0,3,2]=0xB1 (xor1), quad_perm[2,3,0,1]=0x4E (xor2),
// ROW_HALF_MIRROR=0x141 (xor-like over 8), ROW_MIRROR=0x140 (over 16).
template <int CTRL>
__device__ __forceinline__ float dpp_radd(float v) {
    return v + __int_as_float(__builtin_amdgcn_update_dpp(
        __float_as_int(v), __float_as_int(v), CTRL, 0xF, 0xF, false));
}
__device__ __forceinline__ float red16(float v) {   // sum over each 16-lane row; result in all lanes
    v = dpp_radd<0xB1>(v); v = dpp_radd<0x4E>(v);
    v = dpp_radd<0x141>(v); v = dpp_radd<0x140>(v);
    return v;
}
__device__ __forceinline__ float red8(float v) {    // sum over each 8-lane group; result in all lanes
    v = dpp_radd<0xB1>(v); v = dpp_radd<0x4E>(v); v = dpp_radd<0x141>(v);
    return v;
}

// ---------------------------------------------------------------------------
// K0: weight folding + slot init.
// ---------------------------------------------------------------------------
__global__ __launch_bounds__(256) void prep_kernel(
    const float* __restrict__ noise, const float* __restrict__ ln_s_w,
    const float* __restrict__ ln_s_b, const float* __restrict__ slot_mu,
    const float* __restrict__ slot_sigma, const float* __restrict__ Wq,
    const float* __restrict__ Wk, const float* __restrict__ Wv,
    const float* __restrict__ W_ih, float* __restrict__ ws)
{
    int bid = blockIdx.x, t = threadIdx.x;
    if (bid < 32) {
        int i0 = (bid * 256 + t) * 8;
        int d0 = i0 & 127;
        float o[8];
#pragma unroll
        for (int j = 0; j < 8; j++) {
            float sg = slot_sigma[d0 + j];
            float sp = fmaxf(sg, 0.f) + log1pf(expf(-fabsf(sg)));  // softplus
            o[j] = fmaf(sp, noise[i0 + j], slot_mu[d0 + j]);
        }
        float4* dst = (float4*)(ws + OFF_SLOTS + i0);
        dst[0] = make_float4(o[0], o[1], o[2], o[3]);
        dst[1] = make_float4(o[4], o[5], o[6], o[7]);
    } else if (bid < 224) {
        int g = (bid - 32) * 2 + (t >> 7);
        int f = t & 127;
        const float* wih = W_ih + g * ND;
        float acc = 0.f;
        for (int e = 0; e < ND; e++) acc = fmaf(wih[e], Wv[e * ND + f], acc);
        ws[OFF_WC + g * ND + f] = acc;
    } else {
        int dp = (bid - 224) * 2 + (t >> 7);
        int d = t & 127;
        float acc = 0.f;
        for (int e = 0; e < ND; e++) acc = fmaf(Wq[e * ND + d], Wk[e * ND + dp], acc);
        ws[OFF_M2T + dp * ND + d] = SCALE * ln_s_w[d] * acc;
        float c = ln_s_b[d] * acc;
#pragma unroll
        for (int m = 1; m <= 32; m <<= 1) c += __shfl_xor(c, m, 64);
        __shared__ float red[4];
        if ((t & 63) == 0) red[t >> 6] = c;
        __syncthreads();
        if (t == 0)   ws[OFF_QKB + dp] = SCALE * (red[0] + red[1]);
        if (t == 128) ws[OFF_QKB + dp] = SCALE * (red[2] + red[3]);
    }
}

// ---------------------------------------------------------------------------
// qk for iteration 0.  grid 64 (per batch), 512 threads.
// ---------------------------------------------------------------------------
__global__ __launch_bounds__(512) void qk0_kernel(float* __restrict__ ws)
{
    __shared__ float sh_s[NS * ND];
    __shared__ float sh_ln[NS * ND];
    int b = blockIdx.x, t = threadIdx.x;
    sh_s[t]       = ws[OFF_SLOTS + b * NS * ND + t];
    sh_s[t + 512] = ws[OFF_SLOTS + b * NS * ND + t + 512];
    __syncthreads();
    {   // LN(raw): wave w handles slot w, 64 lanes x 2 cols
        int wid = t >> 6, l = t & 63;
        float v0 = sh_s[wid * ND + 2 * l], v1 = sh_s[wid * ND + 2 * l + 1];
        float s1 = v0 + v1, s2 = fmaf(v0, v0, v1 * v1);
#pragma unroll
        for (int m = 1; m <= 32; m <<= 1) { s1 += __shfl_xor(s1, m, 64); s2 += __shfl_xor(s2, m, 64); }
        float mean = s1 * (1.f / 128.f);
        float var = fmaf(-mean, mean, s2 * (1.f / 128.f));
        float tv = var + LNE;
        float rs = rsqrtf(tv); rs = rs * (1.5f - 0.5f * tv * rs * rs);
        sh_ln[wid * ND + 2 * l]     = (v0 - mean) * rs;
        sh_ln[wid * ND + 2 * l + 1] = (v1 - mean) * rs;
    }
    __syncthreads();
    {   // qk[s][dp] = qkb[dp] + ln[s] . M2T[dp]   (8 lanes per output)
        int g = t >> 3, c = t & 7, s = g >> 3, dp0 = g & 7;
        const float4* lp = (const float4*)(sh_ln + s * ND + c * 16);
        float4 l0 = lp[0], l1 = lp[1], l2 = lp[2], l3 = lp[3];
#pragma unroll 2
        for (int j = 0; j < 16; j++) {
            int dp = dp0 + 8 * j;
            const float4* m4 = (const float4*)(ws + OFF_M2T + dp * ND + c * 16);
            float a = dot4f(m4[0], l0) + dot4f(m4[1], l1) + dot4f(m4[2], l2) + dot4f(m4[3], l3);
            a = red8(a);
            if (c == 0) ws[OFF_QK + b * NS * ND + s * ND + dp] = a + ws[OFF_QKB + dp];
        }
    }
}

// ---------------------------------------------------------------------------
// Main fused pass: all butterfly reduces now DPP (VALU), zero LDS shuffles
// in the hot loop.
// ---------------------------------------------------------------------------
__global__ __launch_bounds__(256, 4) void attn_kernel(
    const float* __restrict__ inp, const float* __restrict__ lnw,
    const float* __restrict__ lnb, float* __restrict__ ws)
{
    __shared__ float qk_lds[NS * ND];
    __shared__ float red_lds[4][NS][ND];
    __shared__ float cs_lds[4][NS];
    int t = threadIdx.x;
    int b = blockIdx.x >> 4, chunk = blockIdx.x & 15;
    int w = t >> 6, lane = t & 63;
    int rg = lane >> 4, colg = lane & 15;

    {
        const float4* src = (const float4*)(ws + OFF_QK + b * NS * ND);
        ((float4*)qk_lds)[t] = src[t];
    }
    float wv[8], bv[8];
    {
        const float4* w4 = (const float4*)(lnw + colg * 8);
        const float4* b4 = (const float4*)(lnb + colg * 8);
        float4 wa = w4[0], wb = w4[1], ba = b4[0], bb = b4[1];
        wv[0]=wa.x; wv[1]=wa.y; wv[2]=wa.z; wv[3]=wa.w; wv[4]=wb.x; wv[5]=wb.y; wv[6]=wb.z; wv[7]=wb.w;
        bv[0]=ba.x; bv[1]=ba.y; bv[2]=ba.z; bv[3]=ba.w; bv[4]=bb.x; bv[5]=bb.y; bv[6]=bb.z; bv[7]=bb.w;
    }
    float acc[NS][8];
    float cs[NS];
#pragma unroll
    for (int si = 0; si < NS; si++) {
        cs[si] = 0.f;
#pragma unroll
        for (int j = 0; j < 8; j++) acc[si][j] = 0.f;
    }
    __syncthreads();

    const float* base = inp + ((size_t)b * NN + chunk * ROWS_PER_CHUNK + w * 64 + rg) * ND + colg * 8;
#pragma unroll 2
    for (int q = 0; q < 16; q++) {
        const float* rp = base + q * 4 * ND;
        float4 a0 = *(const float4*)rp;
        float4 a1 = *(const float4*)(rp + 4);
        float x[8] = {a0.x, a0.y, a0.z, a0.w, a1.x, a1.y, a1.z, a1.w};
        float s1 = 0.f, s2 = 0.f;
#pragma unroll
        for (int j = 0; j < 8; j++) { s1 += x[j]; s2 = fmaf(x[j], x[j], s2); }
        s1 = red16(s1); s2 = red16(s2);
        float mean = s1 * (1.f / 128.f);
        float var = fmaf(-mean, mean, s2 * (1.f / 128.f));
        float tv = var + LNE;
        float rs = rsqrtf(tv); rs = rs * (1.5f - 0.5f * tv * rs * rs);
#pragma unroll
        for (int j = 0; j < 8; j++) x[j] = fmaf((x[j] - mean) * rs, wv[j], bv[j]);

        float pd[NS];
#pragma unroll
        for (int si = 0; si < NS; si++) {
            const float4* q4 = (const float4*)(qk_lds + si * ND + colg * 8);
            float4 q0 = q4[0], q1 = q4[1];
            float p = x[0] * q0.x;
            p = fmaf(x[1], q0.y, p); p = fmaf(x[2], q0.z, p); p = fmaf(x[3], q0.w, p);
            p = fmaf(x[4], q1.x, p); p = fmaf(x[5], q1.y, p); p = fmaf(x[6], q1.z, p);
            p = fmaf(x[7], q1.w, p);
            pd[si] = red16(p);
        }
        float mx = fmaxf(fmaxf(fmaxf(pd[0], pd[1]), fmaxf(pd[2], pd[3])),
                         fmaxf(fmaxf(pd[4], pd[5]), fmaxf(pd[6], pd[7])));
        float ev[NS]; float es = 0.f;
#pragma unroll
        for (int si = 0; si < NS; si++) { ev[si] = __expf(pd[si] - mx); es += ev[si]; }
        float r0 = __builtin_amdgcn_rcpf(es);
        float inv = r0 * (2.0f - es * r0);   // 1 NR step
#pragma unroll
        for (int si = 0; si < NS; si++) {
            float p = ev[si] * inv;
            cs[si] += p;
#pragma unroll
            for (int j = 0; j < 8; j++) acc[si][j] = fmaf(p, x[j], acc[si][j]);
        }
    }
    // reduce across the 4 row-groups within the wave (once per pass — shfl OK)
#pragma unroll
    for (int m = 16; m <= 32; m <<= 1) {
#pragma unroll
        for (int si = 0; si < NS; si++) {
            cs[si] += __shfl_xor(cs[si], m, 64);
#pragma unroll
            for (int j = 0; j < 8; j++) acc[si][j] += __shfl_xor(acc[si][j], m, 64);
        }
    }
    if (lane < 16) {
#pragma unroll
        for (int si = 0; si < NS; si++) {
            *(float4*)&red_lds[w][si][lane * 8]     = make_float4(acc[si][0], acc[si][1], acc[si][2], acc[si][3]);
            *(float4*)&red_lds[w][si][lane * 8 + 4] = make_float4(acc[si][4], acc[si][5], acc[si][6], acc[si][7]);
        }
    }
    if (lane == 0) {
#pragma unroll
        for (int si = 0; si < NS; si++) cs_lds[w][si] = cs[si];
    }
    __syncthreads();
    float* pout = ws + OFF_PART + (size_t)(b * CHUNKS + chunk) * (NS * ND);
#pragma unroll
    for (int k = 0; k < 4; k++) {
        int o = t + k * 256;
        pout[o] = red_lds[0][0][o] + red_lds[1][0][o] + red_lds[2][0][o] + red_lds[3][0][o];
    }
    if (t < NS) {
        ws[OFF_PCS + (b * CHUNKS + chunk) * NS + t] =
            cs_lds[0][t] + cs_lds[1][t] + cs_lds[2][t] + cs_lds[3][t];
    }
}

// ---------------------------------------------------------------------------
// Partial reduction: grid 512 = (b, s), 128 threads.
// ---------------------------------------------------------------------------
__global__ __launch_bounds__(128) void reduce_kernel(float* __restrict__ ws)
{
    int b = blockIdx.x >> 3, s = blockIdx.x & 7, t = threadIdx.x;
    const float* part = ws + OFF_PART + (size_t)b * CHUNKS * NS * ND + s * ND;
    float r = 0.f;
#pragma unroll
    for (int p = 0; p < CHUNKS; p++) r += part[p * (NS * ND) + t];
    ws[OFF_UPD + (b * NS + s) * ND + t] = r;
    if (t < 16) {
        float c = ws[OFF_PCS + (b * CHUNKS + t) * NS + s];
        c = red16(c);
        if (t == 0) ws[OFF_CS + b * NS + s] = c;
    }
}

// ---------------------------------------------------------------------------
// GRU + next-qk / final-MLP.  2 blocks per batch (4 slots each), 512 thr.
// ---------------------------------------------------------------------------
template <int LAST>
__global__ __launch_bounds__(512) void gru_kernel(
    const float* __restrict__ W_hh, const float* __restrict__ b_ih,
    const float* __restrict__ b_hh, const float* __restrict__ W1,
    const float* __restrict__ b1, const float* __restrict__ W2,
    const float* __restrict__ b2, const float* __restrict__ ln_m_w,
    const float* __restrict__ ln_m_b, float* __restrict__ ws,
    float* __restrict__ out)
{
    __shared__ float sh_nr[4 * ND];    // normalized updates -> new slots
    __shared__ float sh_sp[4 * ND];    // slots_prev (this half)
    __shared__ float sh_sx[ND];
    __shared__ float sh_cs[4];
    __shared__ float sh_gi[4 * 384];   // reused as h[4][256] in LAST path
    __shared__ float sh_gh[4 * 384];
    __shared__ float sh_ln[4 * ND];
    int b = blockIdx.x >> 1, sh2 = blockIdx.x & 1;
    int t = threadIdx.x;

    float r = ws[OFF_UPD + b * NS * ND + sh2 * 512 + t];
    sh_sp[t] = ws[OFF_SLOTS + b * NS * ND + sh2 * 512 + t];
    if (t < ND) {   // Sx[e] = sum over all 8 slots of raw updates (== Sum_n x[n][e])
        float a = 0.f;
#pragma unroll
        for (int s = 0; s < NS; s++) a += ws[OFF_UPD + b * NS * ND + s * ND + t];
        sh_sx[t] = a;
    }
    if (t < 4) sh_cs[t] = ws[OFF_CS + b * NS + sh2 * 4 + t] + (float)NN * EPSA;
    __syncthreads();
    sh_nr[t] = fmaf(EPSA, sh_sx[t & 127], r) / sh_cs[t >> 7];
    __syncthreads();
    // ---- C: gi = nr@WC^T + b_ih, gh = sp@W_hh^T + b_hh (8 lanes per output)
    int g = t >> 3, c = t & 7;
    int sl = g >> 4, g3 = g & 15;      // local slot 0..3, row phase 0..15
    {
        const float4* np = (const float4*)(sh_nr + sl * ND + c * 16);
        const float4* pp = (const float4*)(sh_sp + sl * ND + c * 16);
        float4 n0 = np[0], n1 = np[1], n2 = np[2], n3 = np[3];
        float4 p0 = pp[0], p1 = pp[1], p2 = pp[2], p3 = pp[3];
#pragma unroll 4
        for (int j = 0; j < 24; j++) {
            int e3 = g3 + 16 * j;
            const float4* wc4 = (const float4*)(ws + OFF_WC + e3 * ND + c * 16);
            const float4* wh4 = (const float4*)(W_hh + e3 * ND + c * 16);
            float ai = dot4f(wc4[0], n0) + dot4f(wc4[1], n1) + dot4f(wc4[2], n2) + dot4f(wc4[3], n3);
            float ah = dot4f(wh4[0], p0) + dot4f(wh4[1], p1) + dot4f(wh4[2], p2) + dot4f(wh4[3], p3);
            ai = red8(ai); ah = red8(ah);
            if (c == 0) {
                sh_gi[sl * 384 + e3] = ai + b_ih[e3];
                sh_gh[sl * 384 + e3] = ah + b_hh[e3];
            }
        }
    }
    __syncthreads();
    // ---- D: gates -> new slots
    {
        int si = t >> 7, d = t & 127;
        float gir = sh_gi[si * 384 + d],       ghr = sh_gh[si * 384 + d];
        float giz = sh_gi[si * 384 + 128 + d], ghz = sh_gh[si * 384 + 128 + d];
        float gin = sh_gi[si * 384 + 256 + d], ghn = sh_gh[si * 384 + 256 + d];
        float rr = 1.f / (1.f + expf(-(gir + ghr)));
        float z  = 1.f / (1.f + expf(-(giz + ghz)));
        float nn_ = tanhf(fmaf(rr, ghn, gin));
        float ns = fmaf(z, sh_sp[t] - nn_, nn_);
        sh_nr[t] = ns;
        if (!LAST) ws[OFF_SLOTS + b * NS * ND + sh2 * 512 + t] = ns;
    }
    __syncthreads();
    // ---- E: LN of new slots (waves 0..3, one slot each)
    {
        int wid = t >> 6, l = t & 63;
        if (wid < 4) {
            float v0 = sh_nr[wid * ND + 2 * l], v1 = sh_nr[wid * ND + 2 * l + 1];
            float s1 = v0 + v1, s2 = fmaf(v0, v0, v1 * v1);
#pragma unroll
            for (int m = 1; m <= 32; m <<= 1) { s1 += __shfl_xor(s1, m, 64); s2 += __shfl_xor(s2, m, 64); }
            float mean = s1 * (1.f / 128.f);
            float var = fmaf(-mean, mean, s2 * (1.f / 128.f));
            float tv = var + LNE;
            float rs = rsqrtf(tv); rs = rs * (1.5f - 0.5f * tv * rs * rs);
            float x0 = (v0 - mean) * rs, x1 = (v1 - mean) * rs;
            if (LAST) {
                x0 = fmaf(x0, ln_m_w[2 * l],     ln_m_b[2 * l]);
                x1 = fmaf(x1, ln_m_w[2 * l + 1], ln_m_b[2 * l + 1]);
            }
            sh_ln[wid * ND + 2 * l]     = x0;
            sh_ln[wid * ND + 2 * l + 1] = x1;
        }
    }
    __syncthreads();
    if (!LAST) {   // ---- F: qk for next iteration
        const float4* lp = (const float4*)(sh_ln + sl * ND + c * 16);
        float4 l0 = lp[0], l1 = lp[1], l2 = lp[2], l3 = lp[3];
#pragma unroll 2
        for (int j = 0; j < 8; j++) {
            int dp = g3 + 16 * j;
            const float4* m4 = (const float4*)(ws + OFF_M2T + dp * ND + c * 16);
            float a = dot4f(m4[0], l0) + dot4f(m4[1], l1) + dot4f(m4[2], l2) + dot4f(m4[3], l3);
            a = red8(a);
            if (c == 0) ws[OFF_QK + b * NS * ND + (sh2 * 4 + sl) * ND + dp] = a + ws[OFF_QKB + dp];
        }
    } else {       // ---- F: MLP
        const float4* lp = (const float4*)(sh_ln + sl * ND + c * 16);
        float4 l0 = lp[0], l1 = lp[1], l2 = lp[2], l3 = lp[3];
#pragma unroll 2
        for (int j = 0; j < 16; j++) {
            int hh = g3 + 16 * j;
            const float4* w14 = (const float4*)(W1 + hh * ND + c * 16);
            float a = dot4f(w14[0], l0) + dot4f(w14[1], l1) + dot4f(w14[2], l2) + dot4f(w14[3], l3);
            a = red8(a);
            if (c == 0) sh_gi[sl * NH + hh] = fmaxf(a + b1[hh], 0.f);
        }
        __syncthreads();
        const float4* hp = (const float4*)(sh_gi + sl * NH + c * 32);
        float4 h0 = hp[0], h1 = hp[1], h2 = hp[2], h3 = hp[3];
        float4 h4 = hp[4], h5 = hp[5], h6 = hp[6], h7 = hp[7];
#pragma unroll 2
        for (int j = 0; j < 8; j++) {
            int d = g3 + 16 * j;
            const float4* w24 = (const float4*)(W2 + d * NH + c * 32);
            float a = dot4f(w24[0], h0) + dot4f(w24[1], h1) + dot4f(w24[2], h2) + dot4f(w24[3], h3)
                    + dot4f(w24[4], h4) + dot4f(w24[5], h5) + dot4f(w24[6], h6) + dot4f(w24[7], h7);
            a = red8(a);
            if (c == 0) out[(size_t)b * NS * ND + (sh2 * 4 + sl) * ND + d] = a + b2[d] + sh_nr[sl * ND + d];
        }
    }
}

// ---------------------------------------------------------------------------
extern "C" void kernel_launch(void* const* d_in, const int* in_sizes, int n_in,
                              void* d_out, int out_size, void* d_ws, size_t ws_size,
                              hipStream_t stream) {
    (void)in_sizes; (void)n_in; (void)out_size; (void)ws_size;
    const float* inputs     = (const float*)d_in[0];
    const float* noise      = (const float*)d_in[1];
    const float* ln_in_w    = (const float*)d_in[2];
    const float* ln_in_b    = (const float*)d_in[3];
    const float* ln_s_w     = (const float*)d_in[4];
    const float* ln_s_b     = (const float*)d_in[5];
    const float* ln_m_w     = (const float*)d_in[6];
    const float* ln_m_b     = (const float*)d_in[7];
    const float* slot_mu    = (const float*)d_in[8];
    const float* slot_sigma = (const float*)d_in[9];
    const float* Wq         = (const float*)d_in[10];
    const float* Wk         = (const float*)d_in[11];
    const float* Wv         = (const float*)d_in[12];
    const float* W_ih       = (const float*)d_in[13];
    const float* W_hh       = (const float*)d_in[14];
    const float* b_ih       = (const float*)d_in[15];
    const float* b_hh       = (const float*)d_in[16];
    const float* W1         = (const float*)d_in[17];
    const float* b1         = (const float*)d_in[18];
    const float* W2         = (const float*)d_in[19];
    const float* b2         = (const float*)d_in[20];
    float* ws  = (float*)d_ws;
    float* out = (float*)d_out;

    hipLaunchKernelGGL(prep_kernel, dim3(288), dim3(256), 0, stream,
                       noise, ln_s_w, ln_s_b, slot_mu, slot_sigma, Wq, Wk, Wv, W_ih, ws);
    hipLaunchKernelGGL(qk0_kernel, dim3(NB), dim3(512), 0, stream, ws);
    for (int it = 0; it < 3; ++it) {
        hipLaunchKernelGGL(attn_kernel, dim3(NB * CHUNKS), dim3(256), 0, stream,
                           inputs, ln_in_w, ln_in_b, ws);
        hipLaunchKernelGGL(reduce_kernel, dim3(NB * NS), dim3(128), 0, stream, ws);
        if (it < 2) {
            hipLaunchKernelGGL((gru_kernel<0>), dim3(NB * 2), dim3(512), 0, stream,
                               W_hh, b_ih, b_hh, W1, b1, W2, b2, ln_m_w, ln_m_b, ws, out);
        } else {
            hipLaunchKernelGGL((gru_kernel<1>), dim3(NB * 2), dim3(512), 0, stream,
                               W_hh, b_ih, b_hh, W1, b1, W2, b2, ln_m_w, ln_m_b, ws, out);
        }
    }
}

// Round 5
// 465.382 us; speedup vs baseline: 3.5181x; 3.5181x over previous
//
#include <hip/hip_runtime.h>
#include <math.h>

// Problem constants
#define NB 64
#define NN 4096
#define ND 128
#define NS 8
#define NH 256
#define CHUNKS 16            // attn blocks per batch
#define ROWS_PER_CHUNK 256   // NN / CHUNKS

static constexpr float EPSA  = 1e-8f;
static constexpr float LNE   = 1e-5f;
static constexpr float SCALE = 0.08838834764831845f;  // 1/sqrt(128)

// ---- workspace layout (float offsets) ----
#define OFF_SLOTS 0                        // [64][8][128]
#define OFF_QK    65536                    // [64][8][128]
#define OFF_WC    131072                   // [384][128]  W_ih @ Wv
#define OFF_M2T   180224                   // [128][128]
#define OFF_QKB   196608                   // [128]
#define OFF_UPD   196736                   // [64][8][128] reduced raw updates
#define OFF_CS    262272                   // [64][8]      reduced colsums
#define OFF_PART  262784                   // [64][16][8][128] partial updates
#define OFF_PCS   1311360                  // [64][16][8]      partial colsums

__device__ __forceinline__ float dot4f(float4 a, float4 b) {
    return fmaf(a.x, b.x, fmaf(a.y, b.y, fmaf(a.z, b.z, a.w * b.w)));
}

// DPP-based lane-group reductions (VALU pipe, no LDS).
template <int CTRL>
__device__ __forceinline__ float dpp_radd(float v) {
    return v + __int_as_float(__builtin_amdgcn_update_dpp(
        __float_as_int(v), __float_as_int(v), CTRL, 0xF, 0xF, false));
}
__device__ __forceinline__ float red16(float v) {   // sum over each 16-lane row; result in all lanes
    v = dpp_radd<0xB1>(v); v = dpp_radd<0x4E>(v);
    v = dpp_radd<0x141>(v); v = dpp_radd<0x140>(v);
    return v;
}
__device__ __forceinline__ float red8(float v) {    // sum over each 8-lane group; result in all lanes
    v = dpp_radd<0xB1>(v); v = dpp_radd<0x4E>(v); v = dpp_radd<0x141>(v);
    return v;
}

// ---------------------------------------------------------------------------
// K0: weight folding + slot init.
// ---------------------------------------------------------------------------
__global__ __launch_bounds__(256) void prep_kernel(
    const float* __restrict__ noise, const float* __restrict__ ln_s_w,
    const float* __restrict__ ln_s_b, const float* __restrict__ slot_mu,
    const float* __restrict__ slot_sigma, const float* __restrict__ Wq,
    const float* __restrict__ Wk, const float* __restrict__ Wv,
    const float* __restrict__ W_ih, float* __restrict__ ws)
{
    int bid = blockIdx.x, t = threadIdx.x;
    if (bid < 32) {
        int i0 = (bid * 256 + t) * 8;
        int d0 = i0 & 127;
        float o[8];
#pragma unroll
        for (int j = 0; j < 8; j++) {
            float sg = slot_sigma[d0 + j];
            float sp = fmaxf(sg, 0.f) + log1pf(expf(-fabsf(sg)));  // softplus
            o[j] = fmaf(sp, noise[i0 + j], slot_mu[d0 + j]);
        }
        float4* dst = (float4*)(ws + OFF_SLOTS + i0);
        dst[0] = make_float4(o[0], o[1], o[2], o[3]);
        dst[1] = make_float4(o[4], o[5], o[6], o[7]);
    } else if (bid < 224) {
        int g = (bid - 32) * 2 + (t >> 7);
        int f = t & 127;
        const float* wih = W_ih + g * ND;
        float acc = 0.f;
        for (int e = 0; e < ND; e++) acc = fmaf(wih[e], Wv[e * ND + f], acc);
        ws[OFF_WC + g * ND + f] = acc;
    } else {
        int dp = (bid - 224) * 2 + (t >> 7);
        int d = t & 127;
        float acc = 0.f;
        for (int e = 0; e < ND; e++) acc = fmaf(Wq[e * ND + d], Wk[e * ND + dp], acc);
        ws[OFF_M2T + dp * ND + d] = SCALE * ln_s_w[d] * acc;
        float c = ln_s_b[d] * acc;
#pragma unroll
        for (int m = 1; m <= 32; m <<= 1) c += __shfl_xor(c, m, 64);
        __shared__ float red[4];
        if ((t & 63) == 0) red[t >> 6] = c;
        __syncthreads();
        if (t == 0)   ws[OFF_QKB + dp] = SCALE * (red[0] + red[1]);
        if (t == 128) ws[OFF_QKB + dp] = SCALE * (red[2] + red[3]);
    }
}

// ---------------------------------------------------------------------------
// qk for iteration 0.  grid 64 (per batch), 512 threads.
// ---------------------------------------------------------------------------
__global__ __launch_bounds__(512) void qk0_kernel(float* __restrict__ ws)
{
    __shared__ float sh_s[NS * ND];
    __shared__ float sh_ln[NS * ND];
    int b = blockIdx.x, t = threadIdx.x;
    sh_s[t]       = ws[OFF_SLOTS + b * NS * ND + t];
    sh_s[t + 512] = ws[OFF_SLOTS + b * NS * ND + t + 512];
    __syncthreads();
    {   // LN(raw): wave w handles slot w, 64 lanes x 2 cols
        int wid = t >> 6, l = t & 63;
        float v0 = sh_s[wid * ND + 2 * l], v1 = sh_s[wid * ND + 2 * l + 1];
        float s1 = v0 + v1, s2 = fmaf(v0, v0, v1 * v1);
#pragma unroll
        for (int m = 1; m <= 32; m <<= 1) { s1 += __shfl_xor(s1, m, 64); s2 += __shfl_xor(s2, m, 64); }
        float mean = s1 * (1.f / 128.f);
        float var = fmaf(-mean, mean, s2 * (1.f / 128.f));
        float tv = var + LNE;
        float rs = rsqrtf(tv); rs = rs * (1.5f - 0.5f * tv * rs * rs);
        sh_ln[wid * ND + 2 * l]     = (v0 - mean) * rs;
        sh_ln[wid * ND + 2 * l + 1] = (v1 - mean) * rs;
    }
    __syncthreads();
    {   // qk[s][dp] = qkb[dp] + ln[s] . M2T[dp]   (8 lanes per output)
        int g = t >> 3, c = t & 7, s = g >> 3, dp0 = g & 7;
        const float4* lp = (const float4*)(sh_ln + s * ND + c * 16);
        float4 l0 = lp[0], l1 = lp[1], l2 = lp[2], l3 = lp[3];
#pragma unroll 2
        for (int j = 0; j < 16; j++) {
            int dp = dp0 + 8 * j;
            const float4* m4 = (const float4*)(ws + OFF_M2T + dp * ND + c * 16);
            float a = dot4f(m4[0], l0) + dot4f(m4[1], l1) + dot4f(m4[2], l2) + dot4f(m4[3], l3);
            a = red8(a);
            if (c == 0) ws[OFF_QK + b * NS * ND + s * ND + dp] = a + ws[OFF_QKB + dp];
        }
    }
}

// ---------------------------------------------------------------------------
// Main fused pass: DPP reduces; NO occupancy bound (round-4 lesson: the
// (256,4) bound capped VGPRs at 64 -> acc[8][8] spilled -> 1.7 GB scratch).
// ---------------------------------------------------------------------------
__global__ __launch_bounds__(256) void attn_kernel(
    const float* __restrict__ inp, const float* __restrict__ lnw,
    const float* __restrict__ lnb, float* __restrict__ ws)
{
    __shared__ float qk_lds[NS * ND];
    __shared__ float red_lds[4][NS][ND];
    __shared__ float cs_lds[4][NS];
    int t = threadIdx.x;
    int b = blockIdx.x >> 4, chunk = blockIdx.x & 15;
    int w = t >> 6, lane = t & 63;
    int rg = lane >> 4, colg = lane & 15;

    {
        const float4* src = (const float4*)(ws + OFF_QK + b * NS * ND);
        ((float4*)qk_lds)[t] = src[t];
    }
    float wv[8], bv[8];
    {
        const float4* w4 = (const float4*)(lnw + colg * 8);
        const float4* b4 = (const float4*)(lnb + colg * 8);
        float4 wa = w4[0], wb = w4[1], ba = b4[0], bb = b4[1];
        wv[0]=wa.x; wv[1]=wa.y; wv[2]=wa.z; wv[3]=wa.w; wv[4]=wb.x; wv[5]=wb.y; wv[6]=wb.z; wv[7]=wb.w;
        bv[0]=ba.x; bv[1]=ba.y; bv[2]=ba.z; bv[3]=ba.w; bv[4]=bb.x; bv[5]=bb.y; bv[6]=bb.z; bv[7]=bb.w;
    }
    float acc[NS][8];
    float cs[NS];
#pragma unroll
    for (int si = 0; si < NS; si++) {
        cs[si] = 0.f;
#pragma unroll
        for (int j = 0; j < 8; j++) acc[si][j] = 0.f;
    }
    __syncthreads();

    const float* base = inp + ((size_t)b * NN + chunk * ROWS_PER_CHUNK + w * 64 + rg) * ND + colg * 8;
#pragma unroll 2
    for (int q = 0; q < 16; q++) {
        const float* rp = base + q * 4 * ND;
        float4 a0 = *(const float4*)rp;
        float4 a1 = *(const float4*)(rp + 4);
        float x[8] = {a0.x, a0.y, a0.z, a0.w, a1.x, a1.y, a1.z, a1.w};
        float s1 = 0.f, s2 = 0.f;
#pragma unroll
        for (int j = 0; j < 8; j++) { s1 += x[j]; s2 = fmaf(x[j], x[j], s2); }
        s1 = red16(s1); s2 = red16(s2);
        float mean = s1 * (1.f / 128.f);
        float var = fmaf(-mean, mean, s2 * (1.f / 128.f));
        float tv = var + LNE;
        float rs = rsqrtf(tv); rs = rs * (1.5f - 0.5f * tv * rs * rs);
#pragma unroll
        for (int j = 0; j < 8; j++) x[j] = fmaf((x[j] - mean) * rs, wv[j], bv[j]);

        float pd[NS];
#pragma unroll
        for (int si = 0; si < NS; si++) {
            const float4* q4 = (const float4*)(qk_lds + si * ND + colg * 8);
            float4 q0 = q4[0], q1 = q4[1];
            float p = x[0] * q0.x;
            p = fmaf(x[1], q0.y, p); p = fmaf(x[2], q0.z, p); p = fmaf(x[3], q0.w, p);
            p = fmaf(x[4], q1.x, p); p = fmaf(x[5], q1.y, p); p = fmaf(x[6], q1.z, p);
            p = fmaf(x[7], q1.w, p);
            pd[si] = red16(p);
        }
        float mx = fmaxf(fmaxf(fmaxf(pd[0], pd[1]), fmaxf(pd[2], pd[3])),
                         fmaxf(fmaxf(pd[4], pd[5]), fmaxf(pd[6], pd[7])));
        float ev[NS]; float es = 0.f;
#pragma unroll
        for (int si = 0; si < NS; si++) { ev[si] = __expf(pd[si] - mx); es += ev[si]; }
        float r0 = __builtin_amdgcn_rcpf(es);
        float inv = r0 * (2.0f - es * r0);   // 1 NR step
#pragma unroll
        for (int si = 0; si < NS; si++) {
            float p = ev[si] * inv;
            cs[si] += p;
#pragma unroll
            for (int j = 0; j < 8; j++) acc[si][j] = fmaf(p, x[j], acc[si][j]);
        }
    }
    // reduce across the 4 row-groups within the wave (once per pass — shfl OK)
#pragma unroll
    for (int m = 16; m <= 32; m <<= 1) {
#pragma unroll
        for (int si = 0; si < NS; si++) {
            cs[si] += __shfl_xor(cs[si], m, 64);
#pragma unroll
            for (int j = 0; j < 8; j++) acc[si][j] += __shfl_xor(acc[si][j], m, 64);
        }
    }
    if (lane < 16) {
#pragma unroll
        for (int si = 0; si < NS; si++) {
            *(float4*)&red_lds[w][si][lane * 8]     = make_float4(acc[si][0], acc[si][1], acc[si][2], acc[si][3]);
            *(float4*)&red_lds[w][si][lane * 8 + 4] = make_float4(acc[si][4], acc[si][5], acc[si][6], acc[si][7]);
        }
    }
    if (lane == 0) {
#pragma unroll
        for (int si = 0; si < NS; si++) cs_lds[w][si] = cs[si];
    }
    __syncthreads();
    float* pout = ws + OFF_PART + (size_t)(b * CHUNKS + chunk) * (NS * ND);
#pragma unroll
    for (int k = 0; k < 4; k++) {
        int o = t + k * 256;
        pout[o] = red_lds[0][0][o] + red_lds[1][0][o] + red_lds[2][0][o] + red_lds[3][0][o];
    }
    if (t < NS) {
        ws[OFF_PCS + (b * CHUNKS + chunk) * NS + t] =
            cs_lds[0][t] + cs_lds[1][t] + cs_lds[2][t] + cs_lds[3][t];
    }
}

// ---------------------------------------------------------------------------
// Partial reduction: grid 512 = (b, s), 128 threads.
// ---------------------------------------------------------------------------
__global__ __launch_bounds__(128) void reduce_kernel(float* __restrict__ ws)
{
    int b = blockIdx.x >> 3, s = blockIdx.x & 7, t = threadIdx.x;
    const float* part = ws + OFF_PART + (size_t)b * CHUNKS * NS * ND + s * ND;
    float r = 0.f;
#pragma unroll
    for (int p = 0; p < CHUNKS; p++) r += part[p * (NS * ND) + t];
    ws[OFF_UPD + (b * NS + s) * ND + t] = r;
    if (t < 16) {
        float c = ws[OFF_PCS + (b * CHUNKS + t) * NS + s];
        c = red16(c);
        if (t == 0) ws[OFF_CS + b * NS + s] = c;
    }
}

// ---------------------------------------------------------------------------
// GRU + next-qk / final-MLP.  2 blocks per batch (4 slots each), 512 thr.
// ---------------------------------------------------------------------------
template <int LAST>
__global__ __launch_bounds__(512) void gru_kernel(
    const float* __restrict__ W_hh, const float* __restrict__ b_ih,
    const float* __restrict__ b_hh, const float* __restrict__ W1,
    const float* __restrict__ b1, const float* __restrict__ W2,
    const float* __restrict__ b2, const float* __restrict__ ln_m_w,
    const float* __restrict__ ln_m_b, float* __restrict__ ws,
    float* __restrict__ out)
{
    __shared__ float sh_nr[4 * ND];    // normalized updates -> new slots
    __shared__ float sh_sp[4 * ND];    // slots_prev (this half)
    __shared__ float sh_sx[ND];
    __shared__ float sh_cs[4];
    __shared__ float sh_gi[4 * 384];   // reused as h[4][256] in LAST path
    __shared__ float sh_gh[4 * 384];
    __shared__ float sh_ln[4 * ND];
    int b = blockIdx.x >> 1, sh2 = blockIdx.x & 1;
    int t = threadIdx.x;

    float r = ws[OFF_UPD + b * NS * ND + sh2 * 512 + t];
    sh_sp[t] = ws[OFF_SLOTS + b * NS * ND + sh2 * 512 + t];
    if (t < ND) {   // Sx[e] = sum over all 8 slots of raw updates (== Sum_n x[n][e])
        float a = 0.f;
#pragma unroll
        for (int s = 0; s < NS; s++) a += ws[OFF_UPD + b * NS * ND + s * ND + t];
        sh_sx[t] = a;
    }
    if (t < 4) sh_cs[t] = ws[OFF_CS + b * NS + sh2 * 4 + t] + (float)NN * EPSA;
    __syncthreads();
    sh_nr[t] = fmaf(EPSA, sh_sx[t & 127], r) / sh_cs[t >> 7];
    __syncthreads();
    // ---- C: gi = nr@WC^T + b_ih, gh = sp@W_hh^T + b_hh (8 lanes per output)
    int g = t >> 3, c = t & 7;
    int sl = g >> 4, g3 = g & 15;      // local slot 0..3, row phase 0..15
    {
        const float4* np = (const float4*)(sh_nr + sl * ND + c * 16);
        const float4* pp = (const float4*)(sh_sp + sl * ND + c * 16);
        float4 n0 = np[0], n1 = np[1], n2 = np[2], n3 = np[3];
        float4 p0 = pp[0], p1 = pp[1], p2 = pp[2], p3 = pp[3];
#pragma unroll 4
        for (int j = 0; j < 24; j++) {
            int e3 = g3 + 16 * j;
            const float4* wc4 = (const float4*)(ws + OFF_WC + e3 * ND + c * 16);
            const float4* wh4 = (const float4*)(W_hh + e3 * ND + c * 16);
            float ai = dot4f(wc4[0], n0) + dot4f(wc4[1], n1) + dot4f(wc4[2], n2) + dot4f(wc4[3], n3);
            float ah = dot4f(wh4[0], p0) + dot4f(wh4[1], p1) + dot4f(wh4[2], p2) + dot4f(wh4[3], p3);
            ai = red8(ai); ah = red8(ah);
            if (c == 0) {
                sh_gi[sl * 384 + e3] = ai + b_ih[e3];
                sh_gh[sl * 384 + e3] = ah + b_hh[e3];
            }
        }
    }
    __syncthreads();
    // ---- D: gates -> new slots
    {
        int si = t >> 7, d = t & 127;
        float gir = sh_gi[si * 384 + d],       ghr = sh_gh[si * 384 + d];
        float giz = sh_gi[si * 384 + 128 + d], ghz = sh_gh[si * 384 + 128 + d];
        float gin = sh_gi[si * 384 + 256 + d], ghn = sh_gh[si * 384 + 256 + d];
        float rr = 1.f / (1.f + expf(-(gir + ghr)));
        float z  = 1.f / (1.f + expf(-(giz + ghz)));
        float nn_ = tanhf(fmaf(rr, ghn, gin));
        float ns = fmaf(z, sh_sp[t] - nn_, nn_);
        sh_nr[t] = ns;
        if (!LAST) ws[OFF_SLOTS + b * NS * ND + sh2 * 512 + t] = ns;
    }
    __syncthreads();
    // ---- E: LN of new slots (waves 0..3, one slot each)
    {
        int wid = t >> 6, l = t & 63;
        if (wid < 4) {
            float v0 = sh_nr[wid * ND + 2 * l], v1 = sh_nr[wid * ND + 2 * l + 1];
            float s1 = v0 + v1, s2 = fmaf(v0, v0, v1 * v1);
#pragma unroll
            for (int m = 1; m <= 32; m <<= 1) { s1 += __shfl_xor(s1, m, 64); s2 += __shfl_xor(s2, m, 64); }
            float mean = s1 * (1.f / 128.f);
            float var = fmaf(-mean, mean, s2 * (1.f / 128.f));
            float tv = var + LNE;
            float rs = rsqrtf(tv); rs = rs * (1.5f - 0.5f * tv * rs * rs);
            float x0 = (v0 - mean) * rs, x1 = (v1 - mean) * rs;
            if (LAST) {
                x0 = fmaf(x0, ln_m_w[2 * l],     ln_m_b[2 * l]);
                x1 = fmaf(x1, ln_m_w[2 * l + 1], ln_m_b[2 * l + 1]);
            }
            sh_ln[wid * ND + 2 * l]     = x0;
            sh_ln[wid * ND + 2 * l + 1] = x1;
        }
    }
    __syncthreads();
    if (!LAST) {   // ---- F: qk for next iteration
        const float4* lp = (const float4*)(sh_ln + sl * ND + c * 16);
        float4 l0 = lp[0], l1 = lp[1], l2 = lp[2], l3 = lp[3];
#pragma unroll 2
        for (int j = 0; j < 8; j++) {
            int dp = g3 + 16 * j;
            const float4* m4 = (const float4*)(ws + OFF_M2T + dp * ND + c * 16);
            float a = dot4f(m4[0], l0) + dot4f(m4[1], l1) + dot4f(m4[2], l2) + dot4f(m4[3], l3);
            a = red8(a);
            if (c == 0) ws[OFF_QK + b * NS * ND + (sh2 * 4 + sl) * ND + dp] = a + ws[OFF_QKB + dp];
        }
    } else {       // ---- F: MLP
        const float4* lp = (const float4*)(sh_ln + sl * ND + c * 16);
        float4 l0 = lp[0], l1 = lp[1], l2 = lp[2], l3 = lp[3];
#pragma unroll 2
        for (int j = 0; j < 16; j++) {
            int hh = g3 + 16 * j;
            const float4* w14 = (const float4*)(W1 + hh * ND + c * 16);
            float a = dot4f(w14[0], l0) + dot4f(w14[1], l1) + dot4f(w14[2], l2) + dot4f(w14[3], l3);
            a = red8(a);
            if (c == 0) sh_gi[sl * NH + hh] = fmaxf(a + b1[hh], 0.f);
        }
        __syncthreads();
        const float4* hp = (const float4*)(sh_gi + sl * NH + c * 32);
        float4 h0 = hp[0], h1 = hp[1], h2 = hp[2], h3 = hp[3];
        float4 h4 = hp[4], h5 = hp[5], h6 = hp[6], h7 = hp[7];
#pragma unroll 2
        for (int j = 0; j < 8; j++) {
            int d = g3 + 16 * j;
            const float4* w24 = (const float4*)(W2 + d * NH + c * 32);
            float a = dot4f(w24[0], h0) + dot4f(w24[1], h1) + dot4f(w24[2], h2) + dot4f(w24[3], h3)
                    + dot4f(w24[4], h4) + dot4f(w24[5], h5) + dot4f(w24[6], h6) + dot4f(w24[7], h7);
            a = red8(a);
            if (c == 0) out[(size_t)b * NS * ND + (sh2 * 4 + sl) * ND + d] = a + b2[d] + sh_nr[sl * ND + d];
        }
    }
}

// ---------------------------------------------------------------------------
extern "C" void kernel_launch(void* const* d_in, const int* in_sizes, int n_in,
                              void* d_out, int out_size, void* d_ws, size_t ws_size,
                              hipStream_t stream) {
    (void)in_sizes; (void)n_in; (void)out_size; (void)ws_size;
    const float* inputs     = (const float*)d_in[0];
    const float* noise      = (const float*)d_in[1];
    const float* ln_in_w    = (const float*)d_in[2];
    const float* ln_in_b    = (const float*)d_in[3];
    const float* ln_s_w     = (const float*)d_in[4];
    const float* ln_s_b     = (const float*)d_in[5];
    const float* ln_m_w     = (const float*)d_in[6];
    const float* ln_m_b     = (const float*)d_in[7];
    const float* slot_mu    = (const float*)d_in[8];
    const float* slot_sigma = (const float*)d_in[9];
    const float* Wq         = (const float*)d_in[10];
    const float* Wk         = (const float*)d_in[11];
    const float* Wv         = (const float*)d_in[12];
    const float* W_ih       = (const float*)d_in[13];
    const float* W_hh       = (const float*)d_in[14];
    const float* b_ih       = (const float*)d_in[15];
    const float* b_hh       = (const float*)d_in[16];
    const float* W1         = (const float*)d_in[17];
    const float* b1         = (const float*)d_in[18];
    const float* W2         = (const float*)d_in[19];
    const float* b2         = (const float*)d_in[20];
    float* ws  = (float*)d_ws;
    float* out = (float*)d_out;

    hipLaunchKernelGGL(prep_kernel, dim3(288), dim3(256), 0, stream,
                       noise, ln_s_w, ln_s_b, slot_mu, slot_sigma, Wq, Wk, Wv, W_ih, ws);
    hipLaunchKernelGGL(qk0_kernel, dim3(NB), dim3(512), 0, stream, ws);
    for (int it = 0; it < 3; ++it) {
        hipLaunchKernelGGL(attn_kernel, dim3(NB * CHUNKS), dim3(256), 0, stream,
                           inputs, ln_in_w, ln_in_b, ws);
        hipLaunchKernelGGL(reduce_kernel, dim3(NB * NS), dim3(128), 0, stream, ws);
        if (it < 2) {
            hipLaunchKernelGGL((gru_kernel<0>), dim3(NB * 2), dim3(512), 0, stream,
                               W_hh, b_ih, b_hh, W1, b1, W2, b2, ln_m_w, ln_m_b, ws, out);
        } else {
            hipLaunchKernelGGL((gru_kernel<1>), dim3(NB * 2), dim3(512), 0, stream,
                               W_hh, b_ih, b_hh, W1, b1, W2, b2, ln_m_w, ln_m_b, ws, out);
        }
    }
}